// Round 1
// baseline (8794.324 us; speedup 1.0000x reference)
//
#include <hip/hip_runtime.h>
#include <cstdint>
#include <cstddef>

// Problem constants (B=8, N=2048, M=256)
#define NB 8
#define NN 2048
#define MM 256

typedef unsigned long long u64;

// monotone float->uint map; canonicalize -0 to +0 so float ties == key ties
__device__ __forceinline__ unsigned mapf(float f) {
  unsigned u = __float_as_uint(f + 0.f);
  return ((int)u >= 0) ? (u ^ 0x80000000u) : ~u;
}
__device__ __forceinline__ u64 shflx_u64(u64 v, int m) {
  unsigned lo = (unsigned)__shfl_xor((int)(unsigned)v, m);
  unsigned hi = (unsigned)__shfl_xor((int)(v >> 32), m);
  return ((u64)hi << 32) | lo;
}

// L1-bypass load (hits the XCD-local L2): the FAST exchange path.
__device__ __forceinline__ u64 load_sc0(const u64* p) {
  u64 v;
  asm volatile("global_load_dwordx2 %0, %1, off sc0\n\ts_waitcnt vmcnt(0)"
               : "=v"(v) : "v"(p) : "memory");
  return v;
}
// Plain store: write-through L1 into the local L2 (fast path publish).
__device__ __forceinline__ void store_plain(u64* p, u64 v) {
  asm volatile("global_store_dwordx2 %0, %1, off" :: "v"(p), "v"(v) : "memory");
}

// ---------------------------------------------------------------------------
// Phase A: LSTM trajectory + fused Q projection.
// grid(NB, 8) x 1024 thr: flat block id = b + 8*j, so the 8 sibling j-blocks
// of batch b land on ONE XCD under round-robin dispatch (locality heuristic
// only — correctness never depends on it).
//
// Exchange redesign vs previous version:
//  * Waves 2..15 poll the XCD-L2 fast path (Hfast) with a LATCHED policy:
//    at t==1 a one-shot probe checks whether the fast path is coherent
//    (same-XCD placement). If yes -> fast-dominant polling (slow LLC probe
//    only every 16th retry as a safety net). If no -> slow-only. This removes
//    the ~700-900cy LLC detour the old fast/slow alternation took on every
//    guaranteed-miss first poll.
//  * Waves 0/1 (the only waves with global stores: h publish / Qout) DO NOT
//    poll global memory at all: load_sc0's vmcnt(0) would drain their
//    outstanding LLC store acks (~400-700cy) every step, directly on the
//    critical path. Instead waves 8/9 (which acquire the same h-quarters
//    q=0/1) re-publish the validated tagged value into an LDS mirror; waves
//    0/1 spin on LDS (lgkmcnt only). Deadlock-free: writers never wait on
//    readers; tag validates; mirror is poisoned before first use.
//  * LDS layouts made bank-conflict-free: part[buf][q][128] and
//    part2[buf][g*8+q][33] give lane-consecutive writes and reads
//    (old stride-12/stride-36 layouts were 4-way conflicted,
//    SQ_LDS_BANK_CONFLICT = 2.5e7).
// ---------------------------------------------------------------------------
__global__ __launch_bounds__(1024) void lstm_kernel(
    const float* __restrict__ z_g, const float* __restrict__ dec,
    const float* __restrict__ h0, const float* __restrict__ w_ih,
    const float* __restrict__ w_hh, const float* __restrict__ b_ih,
    const float* __restrict__ b_hh, const float* __restrict__ Wq,
    const float* __restrict__ bq, float* __restrict__ Qout,
    u64* __restrict__ Hfast, u64* __restrict__ Hslow)
{
  const int b = blockIdx.x;
  const int j = blockIdx.y;
  const int tid = threadIdx.x;
  const int w = tid >> 6;
  const int lane = tid & 63;
  const int q = w & 7;           // k-quarter: cols [32q, 32q+32)
  const int rg = w >> 3;         // row-group
  const int lr = rg * 64 + lane; // 0..127 local gate row
  const int g = lr >> 5;         // gate 0..3 (i,f,g,o)
  const int mi = lr & 31;
  const int grow = g * 256 + 32 * j + mi;

  __shared__ __align__(16) float part[2][8][128];   // gate partials [q][lr]
  __shared__ __align__(16) float part2[2][32][33];  // q partials [g*8+q][mi]
  __shared__ __align__(16) u64 hmir[8][32];         // tagged h mirror (waves 0/1)

  // poison the mirror so waves 0/1's first spin can't see a live tag
  if (tid < 256) ((u64*)hmir)[tid] = 0xAAAAAAAAAAAAAAAAull;

  // recurrent weights -> 32 registers (8 float4, constant-indexed)
  float wreg[32];
  {
    const float* wr = w_hh + (size_t)grow * MM + 32 * q;
    #pragma unroll
    for (int i = 0; i < 8; ++i) {
      float4 v = *(const float4*)(wr + 4 * i);
      wreg[4 * i + 0] = v.x; wreg[4 * i + 1] = v.y;
      wreg[4 * i + 2] = v.z; wreg[4 * i + 3] = v.w;
    }
  }
  // Wq slice: row 32j+mi, cols [32q+8g, 32q+8g+8)
  float wqa[8];
  {
    const float* wr = Wq + (size_t)(32 * j + mi) * MM + 32 * q + 8 * g;
    float4 w0 = *(const float4*)(wr);
    float4 w1 = *(const float4*)(wr + 4);
    wqa[0] = w0.x; wqa[1] = w0.y; wqa[2] = w0.z; wqa[3] = w0.w;
    wqa[4] = w1.x; wqa[5] = w1.y; wqa[6] = w1.z; wqa[7] = w1.w;
  }
  const float bqv = (w == 1 && lane < 32) ? bq[32 * j + lane] : 0.f;

  // xb = dec@w_ih.T + b_ih + b_hh partials via part[0]
  {
    float p = 0.f;
    const float* wr = w_ih + (size_t)grow * MM + 32 * q;
    #pragma unroll
    for (int i = 0; i < 8; ++i) {
      float4 wv = *(const float4*)(wr + 4 * i);
      float4 dv = *(const float4*)(dec + 32 * q + 4 * i);
      p += wv.x * dv.x + wv.y * dv.y + wv.z * dv.z + wv.w * dv.w;
    }
    part[0][q][lr] = p;
  }
  __syncthreads();

  // wave 0: xb for its two cell rows (lane, lane+64) -> registers
  float xbA = 0.f, xbB = 0.f, c_my = 0.f;
  if (w == 0) {
    #pragma unroll
    for (int rr = 0; rr < 2; ++rr) {
      const int lr2 = lane + rr * 64;
      const int g2 = lr2 >> 5, mi2 = lr2 & 31;
      const int grow2 = g2 * 256 + 32 * j + mi2;
      float xb = b_ih[grow2] + b_hh[grow2];
      #pragma unroll
      for (int qq = 0; qq < 8; ++qq) xb += part[0][qq][lr2];
      if (rr == 0) xbA = xb; else xbB = xb;
    }
    if (lane < 32) c_my = z_g[b * MM + 32 * j + lane];
  }
  __syncthreads();

  u64* Hf = Hfast + (size_t)b * 512;
  u64* Hs = Hslow + (size_t)b * 512;
  const int hidx = 32 * q + (lane & 31);
  int fastok = 1;   // latched at t==1 (wave-uniform via __all)

  for (int t = 0; t <= NN; ++t) {
    // ---- acquire h^(t) quarter into registers ----
    int hvi;
    if (t == 0) {
      hvi = __float_as_int(h0[hidx]);
    } else if (w < 2) {
      // waves 0/1: spin on the LDS mirror (lgkmcnt only; never drains the
      // outstanding Hf/Hs/Qout global-store acks these waves carry)
      u64 v;
      for (;;) {
        v = __hip_atomic_load(&hmir[q][lane & 31], __ATOMIC_RELAXED,
                              __HIP_MEMORY_SCOPE_WORKGROUP);
        if (__all((int)((unsigned)(v >> 32) == (unsigned)t))) break;
      }
      hvi = (int)(unsigned)v;
    } else {
      const int off = ((t & 1) << 8) + hidx;
      u64 v = load_sc0(Hf + off);
      int tries = 0;
      for (;;) {
        const bool ok = ((unsigned)(v >> 32) == (unsigned)t);
        if (__all((int)ok)) break;
        ++tries;
        if (!ok) {
          const bool useslow = fastok ? ((tries & 15) == 15) : true;
          v = useslow ? __hip_atomic_load(Hs + off, __ATOMIC_RELAXED,
                                          __HIP_MEMORY_SCOPE_AGENT)
                      : load_sc0(Hf + off);
        }
      }
      if (t == 1) {
        // one-shot placement probe: if the fast path is coherent, the line
        // must carry tag 1 by now (publish preceded our success)
        const u64 pv = load_sc0(Hf + off);
        fastok = __all((int)((unsigned)(pv >> 32) == 1u)) ? 1 : 0;
      }
      // waves 8/9 mirror quarters 0/1 into LDS for waves 0/1
      if ((w == 8 || w == 9) && lane < 32)
        __hip_atomic_store(&hmir[q][lane], v, __ATOMIC_RELAXED,
                           __HIP_MEMORY_SCOPE_WORKGROUP);
      hvi = (int)(unsigned)v;
    }

    // ---- matvec partial: 4 interleaved fma chains over the quarter ----
    {
      float a0 = 0.f, a1 = 0.f, a2 = 0.f, a3 = 0.f;
      #pragma unroll
      for (int k = 0; k < 32; k += 4) {
        a0 = fmaf(__uint_as_float((unsigned)__builtin_amdgcn_readlane(hvi, k + 0)), wreg[k + 0], a0);
        a1 = fmaf(__uint_as_float((unsigned)__builtin_amdgcn_readlane(hvi, k + 1)), wreg[k + 1], a1);
        a2 = fmaf(__uint_as_float((unsigned)__builtin_amdgcn_readlane(hvi, k + 2)), wreg[k + 2], a2);
        a3 = fmaf(__uint_as_float((unsigned)__builtin_amdgcn_readlane(hvi, k + 3)), wreg[k + 3], a3);
      }
      part[t & 1][q][lr] = (a0 + a1) + (a2 + a3);
    }

    // ---- q-projection partial from the same quarter (h^(t)) ----
    {
      float qa = 0.f;
      #pragma unroll
      for (int i = 0; i < 8; ++i) {
        const float hh = __uint_as_float((unsigned)__shfl(hvi, 8 * g + i));
        qa = fmaf(hh, wqa[i], qa);
      }
      if (t > 0) part2[t & 1][g * 8 + q][mi] = qa;
    }
    __syncthreads();   // the ONE barrier per step

    // ---- wave 0: cell update on 64 lanes (2 gate rows each) + publish ----
    if (w == 0 && t < NN) {
      float vA = xbA, vB = xbB;
      #pragma unroll
      for (int qq = 0; qq < 8; ++qq) {
        vA += part[t & 1][qq][lane];
        vB += part[t & 1][qq][lane + 64];
      }
      // lanes<32: vA=i-gate, vB=g-gate; lanes>=32: vA=f-gate, vB=o-gate
      const float s1 = 1.f / (1.f + __expf(-vA));               // sigmoid
      const float e  = __expf(((lane < 32) ? -2.f : -1.f) * vB);
      const float s2 = (lane < 32) ? (2.f / (1.f + e) - 1.f)    // tanh
                                   : (1.f / (1.f + e));         // sigmoid
      const float fo1 = __shfl_xor(s1, 32);   // f (at lanes<32)
      const float fo2 = __shfl_xor(s2, 32);   // o (at lanes<32)
      if (lane < 32) {
        c_my = fo1 * c_my + s1 * s2;
        const float e2 = __expf(-2.f * c_my);
        const float hn = fo2 * (2.f / (1.f + e2) - 1.f);
        const u64 pk = ((u64)(unsigned)(t + 1) << 32) | (u64)__float_as_uint(hn);
        const int so = (((t + 1) & 1) << 8) + 32 * j + lane;
        store_plain(Hf + so, pk);                                  // local L2
        __hip_atomic_store(Hs + so, pk, __ATOMIC_RELAXED,
                           __HIP_MEMORY_SCOPE_AGENT);              // LLC truth
      }
    }

    // ---- wave 1: reduce q partials -> Qout row t-1 (off critical path) ----
    if (w == 1 && t > 0 && lane < 32) {
      float s = 0.f;
      #pragma unroll
      for (int p = 0; p < 32; ++p) s += part2[t & 1][p][lane];
      Qout[((size_t)b * NN + (t - 1)) * MM + 32 * j + lane] = s + bqv;
    }
  }
}

// ---------------------------------------------------------------------------
// C = A @ B^T (+ col bias). 128x128 tile, 256 threads, 8x8 micro-tile.
// ---------------------------------------------------------------------------
__global__ __launch_bounds__(256) void gemm128(
    const float* __restrict__ A, const float* __restrict__ B,
    float* __restrict__ C, const float* __restrict__ bias,
    int K, int Ncol, long sA, long sB, long sC)
{
  __shared__ __align__(16) float As[32][132];
  __shared__ __align__(16) float Bs[32][132];
  const int tid = threadIdx.x;
  const int tx = tid & 15;
  const int ty = tid >> 4;
  const int row0 = blockIdx.y * 128;
  const int col0 = blockIdx.x * 128;
  const float* Ab = A + (size_t)blockIdx.z * (size_t)sA;
  const float* Bb = B + (size_t)blockIdx.z * (size_t)sB;
  float* Cb = C + (size_t)blockIdx.z * (size_t)sC;

  float acc[8][8];
  #pragma unroll
  for (int i = 0; i < 8; ++i)
    #pragma unroll
    for (int jj = 0; jj < 8; ++jj) acc[i][jj] = 0.f;

  for (int k0 = 0; k0 < K; k0 += 32) {
    #pragma unroll
    for (int it = 0; it < 4; ++it) {
      const int idx = tid + it * 256;
      const int r = idx >> 3;
      const int c4 = (idx & 7) << 2;
      float4 va = *(const float4*)(Ab + (size_t)(row0 + r) * K + k0 + c4);
      float4 vb = *(const float4*)(Bb + (size_t)(col0 + r) * K + k0 + c4);
      As[c4 + 0][r] = va.x; As[c4 + 1][r] = va.y;
      As[c4 + 2][r] = va.z; As[c4 + 3][r] = va.w;
      Bs[c4 + 0][r] = vb.x; Bs[c4 + 1][r] = vb.y;
      Bs[c4 + 2][r] = vb.z; Bs[c4 + 3][r] = vb.w;
    }
    __syncthreads();
    #pragma unroll
    for (int kk = 0; kk < 32; ++kk) {
      float4 a0 = *(const float4*)&As[kk][ty * 4];
      float4 a1 = *(const float4*)&As[kk][64 + ty * 4];
      float4 b0 = *(const float4*)&Bs[kk][tx * 4];
      float4 b1 = *(const float4*)&Bs[kk][64 + tx * 4];
      const float av[8] = {a0.x, a0.y, a0.z, a0.w, a1.x, a1.y, a1.z, a1.w};
      const float bv[8] = {b0.x, b0.y, b0.z, b0.w, b1.x, b1.y, b1.z, b1.w};
      #pragma unroll
      for (int i = 0; i < 8; ++i)
        #pragma unroll
        for (int jj = 0; jj < 8; ++jj)
          acc[i][jj] = fmaf(av[i], bv[jj], acc[i][jj]);
    }
    __syncthreads();
  }

  #pragma unroll
  for (int i = 0; i < 8; ++i) {
    const int r = row0 + ((i < 4) ? (ty * 4 + i) : (64 + ty * 4 + i - 4));
    float* cp = Cb + (size_t)r * Ncol + col0;
    float4 o0, o1;
    float* o0p = &o0.x; float* o1p = &o1.x;
    #pragma unroll
    for (int jj = 0; jj < 4; ++jj) {
      float v0 = acc[i][jj], v1 = acc[i][jj + 4];
      if (bias) {
        v0 += bias[col0 + tx * 4 + jj];
        v1 += bias[col0 + 64 + tx * 4 + jj];
      }
      o0p[jj] = v0; o1p[jj] = v1;
    }
    *(float4*)(cp + tx * 4) = o0;
    *(float4*)(cp + 64 + tx * 4) = o1;
  }
}

// ---------------------------------------------------------------------------
// Phase D: exact greedy masked argmax chain, one block (512 thr) per batch.
// ---------------------------------------------------------------------------
__global__ __launch_bounds__(512) void select_block(
    const float* __restrict__ S, int* __restrict__ sel)
{
  const int b = blockIdx.x;
  const int tid = threadIdx.x;
  const int w = tid >> 6;          // 0..7
  const int lane = tid & 63;
  const float* Sb = S + (size_t)b * NN * NN + 4 * tid;
  int* selb = sel + b * NN;

  __shared__ u64 partial[2][8];

  for (int i = tid; i < NN; i += 512) selb[i] = 0x7fffffff;
  __syncthreads();

  unsigned mybits = 0;                 // used flags for my 4 columns
  const unsigned base = 2047u - 4u * (unsigned)tid;

  auto stepf = [&](float4 v, int t) {
    u64 k0 = (mybits & 1u) ? 0 : (((u64)mapf(v.x) << 32) | (base - 0u));
    u64 k1 = (mybits & 2u) ? 0 : (((u64)mapf(v.y) << 32) | (base - 1u));
    u64 k2 = (mybits & 4u) ? 0 : (((u64)mapf(v.z) << 32) | (base - 2u));
    u64 k3 = (mybits & 8u) ? 0 : (((u64)mapf(v.w) << 32) | (base - 3u));
    u64 k = k0 > k1 ? k0 : k1;
    if (k2 > k) k = k2;
    if (k3 > k) k = k3;
    #pragma unroll
    for (int off = 1; off < 64; off <<= 1) {
      u64 o = shflx_u64(k, off);
      if (o > k) k = o;
    }
    if (lane == 0) partial[t & 1][w] = k;
    __syncthreads();
    u64 pk = partial[t & 1][lane & 7];
    #pragma unroll
    for (int off = 1; off < 8; off <<= 1) {
      u64 o = shflx_u64(pk, off);
      if (o > pk) pk = o;
    }
    const int idx = 2047 - (int)(pk & 0x7ff);
    if ((idx >> 2) == tid) mybits |= 1u << (idx & 3);
    if (tid == 0) selb[idx] = t;
  };

  float4 r0 = *(const float4*)(Sb + (size_t)0 * NN);
  float4 r1 = *(const float4*)(Sb + (size_t)1 * NN);
  float4 r2 = *(const float4*)(Sb + (size_t)2 * NN);
  float4 r3 = *(const float4*)(Sb + (size_t)3 * NN);
  for (int t = 0; t < NN; t += 4) {
    const size_t p4 = (size_t)((t + 4 < NN) ? t + 4 : NN - 1) * NN;
    const size_t p5 = (size_t)((t + 5 < NN) ? t + 5 : NN - 1) * NN;
    const size_t p6 = (size_t)((t + 6 < NN) ? t + 6 : NN - 1) * NN;
    const size_t p7 = (size_t)((t + 7 < NN) ? t + 7 : NN - 1) * NN;
    stepf(r0, t);     r0 = *(const float4*)(Sb + p4);
    stepf(r1, t + 1); r1 = *(const float4*)(Sb + p5);
    stepf(r2, t + 2); r2 = *(const float4*)(Sb + p6);
    stepf(r3, t + 3); r3 = *(const float4*)(Sb + p7);
  }
}

// ---------------------------------------------------------------------------
// Phase E: in-place masked softmax per row. Row t masks n iff sel[n] < t.
// ---------------------------------------------------------------------------
__global__ __launch_bounds__(256) void softmax_kernel(
    float* __restrict__ out, const int* __restrict__ sel)
{
  const int t = blockIdx.x;
  const int b = blockIdx.y;
  const int tid = threadIdx.x;
  float* row = out + ((size_t)b * NN + t) * NN;
  const int* selb = sel + b * NN;
  __shared__ float red[8];

  float v[8];
  int sl[8];
  #pragma unroll
  for (int u = 0; u < 2; ++u) {
    float4 f = *(const float4*)(row + u * 1024 + tid * 4);
    int4 s4 = *(const int4*)(selb + u * 1024 + tid * 4);
    v[u * 4 + 0] = f.x; v[u * 4 + 1] = f.y; v[u * 4 + 2] = f.z; v[u * 4 + 3] = f.w;
    sl[u * 4 + 0] = s4.x; sl[u * 4 + 1] = s4.y; sl[u * 4 + 2] = s4.z; sl[u * 4 + 3] = s4.w;
  }

  float mx = -3.0e38f;
  #pragma unroll
  for (int e = 0; e < 8; ++e)
    if (sl[e] >= t) mx = fmaxf(mx, v[e]);
  #pragma unroll
  for (int off = 1; off < 64; off <<= 1) mx = fmaxf(mx, __shfl_xor(mx, off));
  if ((tid & 63) == 0) red[tid >> 6] = mx;
  __syncthreads();
  mx = fmaxf(fmaxf(red[0], red[1]), fmaxf(red[2], red[3]));

  float e8[8];
  float sum = 0.f;
  #pragma unroll
  for (int e = 0; e < 8; ++e) {
    float ex = (sl[e] >= t) ? __expf(v[e] - mx) : 0.f;
    e8[e] = ex;
    sum += ex;
  }
  #pragma unroll
  for (int off = 1; off < 64; off <<= 1) sum += __shfl_xor(sum, off);
  if ((tid & 63) == 0) red[4 + (tid >> 6)] = sum;
  __syncthreads();
  sum = red[4] + red[5] + red[6] + red[7];
  const float inv = 1.f / sum;

  #pragma unroll
  for (int u = 0; u < 2; ++u) {
    float4 o;
    o.x = e8[u * 4 + 0] * inv; o.y = e8[u * 4 + 1] * inv;
    o.z = e8[u * 4 + 2] * inv; o.w = e8[u * 4 + 3] * inv;
    *(float4*)(row + u * 1024 + tid * 4) = o;
  }
}

// ---------------------------------------------------------------------------
// ws layout (floats): keys[4194304] | Q[4194304] | Hfast(u64 4096) |
//                     Hslow(u64 4096) | sel[16384]   ~ 33.7 MB
// ---------------------------------------------------------------------------
extern "C" void kernel_launch(void* const* d_in, const int* in_sizes, int n_in,
                              void* d_out, int out_size, void* d_ws, size_t ws_size,
                              hipStream_t stream)
{
  (void)in_sizes; (void)n_in; (void)out_size; (void)ws_size;
  const float* emb  = (const float*)d_in[0];
  const float* z_g  = (const float*)d_in[1];
  const float* dec  = (const float*)d_in[2];
  const float* h0   = (const float*)d_in[3];
  const float* w_ih = (const float*)d_in[4];
  const float* w_hh = (const float*)d_in[5];
  const float* b_ih = (const float*)d_in[6];
  const float* b_hh = (const float*)d_in[7];
  const float* Wq   = (const float*)d_in[8];
  const float* bq   = (const float*)d_in[9];
  const float* Wk   = (const float*)d_in[10];
  const float* bk   = (const float*)d_in[11];
  float* out = (float*)d_out;
  float* ws  = (float*)d_ws;

  float* keys  = ws;
  float* Q     = ws + 4194304;
  u64*   Hfast = (u64*)(ws + 8388608);
  u64*   Hslow = (u64*)(ws + 8396800);
  int*   sel   = (int*)(ws + 8404992);

  lstm_kernel<<<dim3(NB, 8), 1024, 0, stream>>>(
      z_g, dec, h0, w_ih, w_hh, b_ih, b_hh, Wq, bq, Q, Hfast, Hslow);

  // keys = emb @ Wk.T + bk  ([16384,256] x [256,256]^T)
  gemm128<<<dim3(MM / 128, (NB * NN) / 128, 1), 256, 0, stream>>>(
      emb, Wk, keys, bk, MM, MM, 0, 0, 0);

  // S[b] = Q[b] @ keys[b].T -> straight into d_out
  gemm128<<<dim3(NN / 128, NN / 128, NB), 256, 0, stream>>>(
      Q, keys, out, nullptr, MM, NN,
      (long)NN * MM, (long)NN * MM, (long)NN * NN);

  select_block<<<NB, 512, 0, stream>>>(out, sel);

  softmax_kernel<<<dim3(NN, NB), 256, 0, stream>>>(out, sel);
}

// Round 2
// 5034.856 us; speedup vs baseline: 1.7467x; 1.7467x over previous
//
#include <hip/hip_runtime.h>
#include <cstdint>
#include <cstddef>

// Problem constants (B=8, N=2048, M=256)
#define NB 8
#define NN 2048
#define MM 256

typedef unsigned long long u64;

// monotone float->uint map; canonicalize -0 to +0 so float ties == key ties
__device__ __forceinline__ unsigned mapf(float f) {
  unsigned u = __float_as_uint(f + 0.f);
  return ((int)u >= 0) ? (u ^ 0x80000000u) : ~u;
}
__device__ __forceinline__ u64 shflx_u64(u64 v, int m) {
  unsigned lo = (unsigned)__shfl_xor((int)(unsigned)v, m);
  unsigned hi = (unsigned)__shfl_xor((int)(v >> 32), m);
  return ((u64)hi << 32) | lo;
}

// ---------------------------------------------------------------------------
// Phase A: LSTM trajectory + fused Q projection.
// grid(NB, 8) x 1024 thr. Block (j,b) owns m in [32j,32j+32) -> 128 gate rows;
// thread holds 32 w_hh weights. Exchange: tagged u64 (h | (t+1)<<32) published
// as an agent-scope atomic store (LLC = the coherence point). ALL waves poll
// the LLC word directly (slow-only): every probe is globally fresh (no stale
// per-XCD L2 line can satisfy it), progress is guaranteed, and the probe
// period (~600-800cy) beats round-0's serial fast+slow alternation (~900cy).
// Round-1's latched fast-path experiment regressed 2.3x: a one-shot coherence
// probe at t==1 misclassifies (first touch refills from LLC and looks
// coherent), after which polling keeps the stale L2 line resident forever.
// Wave 0's store-ack drain concern is void: its first poll after publish is a
// guaranteed miss, which absorbs the drain.
// Partial buffers double-buffered by t&1; ONE barrier per step.
// LDS layouts are bank-conflict-free (verified: SQ_LDS_BANK_CONFLICT 2.5e7->0):
//   part[buf][q][128]  (lane-consecutive writes and reads)
//   part2[buf][g*8+q][33]
// ---------------------------------------------------------------------------
__global__ __launch_bounds__(1024) void lstm_kernel(
    const float* __restrict__ z_g, const float* __restrict__ dec,
    const float* __restrict__ h0, const float* __restrict__ w_ih,
    const float* __restrict__ w_hh, const float* __restrict__ b_ih,
    const float* __restrict__ b_hh, const float* __restrict__ Wq,
    const float* __restrict__ bq, float* __restrict__ Qout,
    u64* __restrict__ Hslow)
{
  const int b = blockIdx.x;
  const int j = blockIdx.y;
  const int tid = threadIdx.x;
  const int w = tid >> 6;
  const int lane = tid & 63;
  const int q = w & 7;           // k-quarter: cols [32q, 32q+32)
  const int rg = w >> 3;         // row-group
  const int lr = rg * 64 + lane; // 0..127 local gate row
  const int g = lr >> 5;         // gate 0..3 (i,f,g,o)
  const int mi = lr & 31;
  const int grow = g * 256 + 32 * j + mi;

  __shared__ __align__(16) float part[2][8][128];   // gate partials [q][lr]
  __shared__ __align__(16) float part2[2][32][33];  // q partials [g*8+q][mi]

  // recurrent weights -> 32 registers (8 float4, constant-indexed)
  float wreg[32];
  {
    const float* wr = w_hh + (size_t)grow * MM + 32 * q;
    #pragma unroll
    for (int i = 0; i < 8; ++i) {
      float4 v = *(const float4*)(wr + 4 * i);
      wreg[4 * i + 0] = v.x; wreg[4 * i + 1] = v.y;
      wreg[4 * i + 2] = v.z; wreg[4 * i + 3] = v.w;
    }
  }
  // Wq slice: row 32j+mi, cols [32q+8g, 32q+8g+8)
  float wqa[8];
  {
    const float* wr = Wq + (size_t)(32 * j + mi) * MM + 32 * q + 8 * g;
    float4 w0 = *(const float4*)(wr);
    float4 w1 = *(const float4*)(wr + 4);
    wqa[0] = w0.x; wqa[1] = w0.y; wqa[2] = w0.z; wqa[3] = w0.w;
    wqa[4] = w1.x; wqa[5] = w1.y; wqa[6] = w1.z; wqa[7] = w1.w;
  }
  const float bqv = (w == 1 && lane < 32) ? bq[32 * j + lane] : 0.f;

  // xb = dec@w_ih.T + b_ih + b_hh partials via part[0]
  {
    float p = 0.f;
    const float* wr = w_ih + (size_t)grow * MM + 32 * q;
    #pragma unroll
    for (int i = 0; i < 8; ++i) {
      float4 wv = *(const float4*)(wr + 4 * i);
      float4 dv = *(const float4*)(dec + 32 * q + 4 * i);
      p += wv.x * dv.x + wv.y * dv.y + wv.z * dv.z + wv.w * dv.w;
    }
    part[0][q][lr] = p;
  }
  __syncthreads();

  // wave 0: xb for its two cell rows (lane, lane+64) -> registers
  float xbA = 0.f, xbB = 0.f, c_my = 0.f;
  if (w == 0) {
    #pragma unroll
    for (int rr = 0; rr < 2; ++rr) {
      const int lr2 = lane + rr * 64;
      const int g2 = lr2 >> 5, mi2 = lr2 & 31;
      const int grow2 = g2 * 256 + 32 * j + mi2;
      float xb = b_ih[grow2] + b_hh[grow2];
      #pragma unroll
      for (int qq = 0; qq < 8; ++qq) xb += part[0][qq][lr2];
      if (rr == 0) xbA = xb; else xbB = xb;
    }
    if (lane < 32) c_my = z_g[b * MM + 32 * j + lane];
  }
  __syncthreads();

  u64* Hs = Hslow + (size_t)b * 512;
  const int hidx = 32 * q + (lane & 31);

  for (int t = 0; t <= NN; ++t) {
    // ---- acquire h^(t) quarter into registers (LLC-coherent poll) ----
    int hvi;
    if (t == 0) {
      hvi = __float_as_int(h0[hidx]);
    } else {
      const int off = ((t & 1) << 8) + hidx;
      u64 v = __hip_atomic_load(Hs + off, __ATOMIC_RELAXED,
                                __HIP_MEMORY_SCOPE_AGENT);
      for (;;) {
        if (__all((int)((unsigned)(v >> 32) == (unsigned)t))) break;
        v = __hip_atomic_load(Hs + off, __ATOMIC_RELAXED,
                              __HIP_MEMORY_SCOPE_AGENT);
      }
      hvi = (int)(unsigned)v;
    }

    // ---- matvec partial: 4 interleaved fma chains over the quarter ----
    {
      float a0 = 0.f, a1 = 0.f, a2 = 0.f, a3 = 0.f;
      #pragma unroll
      for (int k = 0; k < 32; k += 4) {
        a0 = fmaf(__uint_as_float((unsigned)__builtin_amdgcn_readlane(hvi, k + 0)), wreg[k + 0], a0);
        a1 = fmaf(__uint_as_float((unsigned)__builtin_amdgcn_readlane(hvi, k + 1)), wreg[k + 1], a1);
        a2 = fmaf(__uint_as_float((unsigned)__builtin_amdgcn_readlane(hvi, k + 2)), wreg[k + 2], a2);
        a3 = fmaf(__uint_as_float((unsigned)__builtin_amdgcn_readlane(hvi, k + 3)), wreg[k + 3], a3);
      }
      part[t & 1][q][lr] = (a0 + a1) + (a2 + a3);
    }

    // ---- q-projection partial from the same quarter (h^(t)) ----
    {
      float qa = 0.f;
      #pragma unroll
      for (int i = 0; i < 8; ++i) {
        const float hh = __uint_as_float((unsigned)__shfl(hvi, 8 * g + i));
        qa = fmaf(hh, wqa[i], qa);
      }
      if (t > 0) part2[t & 1][g * 8 + q][mi] = qa;
    }
    __syncthreads();   // the ONE barrier per step

    // ---- wave 0: cell update on 64 lanes (2 gate rows each) + publish ----
    if (w == 0 && t < NN) {
      float vA = xbA, vB = xbB;
      #pragma unroll
      for (int qq = 0; qq < 8; ++qq) {
        vA += part[t & 1][qq][lane];
        vB += part[t & 1][qq][lane + 64];
      }
      // lanes<32: vA=i-gate, vB=g-gate; lanes>=32: vA=f-gate, vB=o-gate
      const float s1 = 1.f / (1.f + __expf(-vA));               // sigmoid
      const float e  = __expf(((lane < 32) ? -2.f : -1.f) * vB);
      const float s2 = (lane < 32) ? (2.f / (1.f + e) - 1.f)    // tanh
                                   : (1.f / (1.f + e));         // sigmoid
      const float fo1 = __shfl_xor(s1, 32);   // f (at lanes<32)
      const float fo2 = __shfl_xor(s2, 32);   // o (at lanes<32)
      if (lane < 32) {
        c_my = fo1 * c_my + s1 * s2;
        const float e2 = __expf(-2.f * c_my);
        const float hn = fo2 * (2.f / (1.f + e2) - 1.f);
        const u64 pk = ((u64)(unsigned)(t + 1) << 32) | (u64)__float_as_uint(hn);
        const int so = (((t + 1) & 1) << 8) + 32 * j + lane;
        __hip_atomic_store(Hs + so, pk, __ATOMIC_RELAXED,
                           __HIP_MEMORY_SCOPE_AGENT);              // LLC truth
      }
    }

    // ---- wave 1: reduce q partials -> Qout row t-1 (off critical path) ----
    if (w == 1 && t > 0 && lane < 32) {
      float s = 0.f;
      #pragma unroll
      for (int p = 0; p < 32; ++p) s += part2[t & 1][p][lane];
      Qout[((size_t)b * NN + (t - 1)) * MM + 32 * j + lane] = s + bqv;
    }
  }
}

// ---------------------------------------------------------------------------
// C = A @ B^T (+ col bias). 128x128 tile, 256 threads, 8x8 micro-tile.
// ---------------------------------------------------------------------------
__global__ __launch_bounds__(256) void gemm128(
    const float* __restrict__ A, const float* __restrict__ B,
    float* __restrict__ C, const float* __restrict__ bias,
    int K, int Ncol, long sA, long sB, long sC)
{
  __shared__ __align__(16) float As[32][132];
  __shared__ __align__(16) float Bs[32][132];
  const int tid = threadIdx.x;
  const int tx = tid & 15;
  const int ty = tid >> 4;
  const int row0 = blockIdx.y * 128;
  const int col0 = blockIdx.x * 128;
  const float* Ab = A + (size_t)blockIdx.z * (size_t)sA;
  const float* Bb = B + (size_t)blockIdx.z * (size_t)sB;
  float* Cb = C + (size_t)blockIdx.z * (size_t)sC;

  float acc[8][8];
  #pragma unroll
  for (int i = 0; i < 8; ++i)
    #pragma unroll
    for (int jj = 0; jj < 8; ++jj) acc[i][jj] = 0.f;

  for (int k0 = 0; k0 < K; k0 += 32) {
    #pragma unroll
    for (int it = 0; it < 4; ++it) {
      const int idx = tid + it * 256;
      const int r = idx >> 3;
      const int c4 = (idx & 7) << 2;
      float4 va = *(const float4*)(Ab + (size_t)(row0 + r) * K + k0 + c4);
      float4 vb = *(const float4*)(Bb + (size_t)(col0 + r) * K + k0 + c4);
      As[c4 + 0][r] = va.x; As[c4 + 1][r] = va.y;
      As[c4 + 2][r] = va.z; As[c4 + 3][r] = va.w;
      Bs[c4 + 0][r] = vb.x; Bs[c4 + 1][r] = vb.y;
      Bs[c4 + 2][r] = vb.z; Bs[c4 + 3][r] = vb.w;
    }
    __syncthreads();
    #pragma unroll
    for (int kk = 0; kk < 32; ++kk) {
      float4 a0 = *(const float4*)&As[kk][ty * 4];
      float4 a1 = *(const float4*)&As[kk][64 + ty * 4];
      float4 b0 = *(const float4*)&Bs[kk][tx * 4];
      float4 b1 = *(const float4*)&Bs[kk][64 + tx * 4];
      const float av[8] = {a0.x, a0.y, a0.z, a0.w, a1.x, a1.y, a1.z, a1.w};
      const float bv[8] = {b0.x, b0.y, b0.z, b0.w, b1.x, b1.y, b1.z, b1.w};
      #pragma unroll
      for (int i = 0; i < 8; ++i)
        #pragma unroll
        for (int jj = 0; jj < 8; ++jj)
          acc[i][jj] = fmaf(av[i], bv[jj], acc[i][jj]);
    }
    __syncthreads();
  }

  #pragma unroll
  for (int i = 0; i < 8; ++i) {
    const int r = row0 + ((i < 4) ? (ty * 4 + i) : (64 + ty * 4 + i - 4));
    float* cp = Cb + (size_t)r * Ncol + col0;
    float4 o0, o1;
    float* o0p = &o0.x; float* o1p = &o1.x;
    #pragma unroll
    for (int jj = 0; jj < 4; ++jj) {
      float v0 = acc[i][jj], v1 = acc[i][jj + 4];
      if (bias) {
        v0 += bias[col0 + tx * 4 + jj];
        v1 += bias[col0 + 64 + tx * 4 + jj];
      }
      o0p[jj] = v0; o1p[jj] = v1;
    }
    *(float4*)(cp + tx * 4) = o0;
    *(float4*)(cp + 64 + tx * 4) = o1;
  }
}

// ---------------------------------------------------------------------------
// Phase D: exact greedy masked argmax chain, one block (512 thr) per batch.
// ---------------------------------------------------------------------------
__global__ __launch_bounds__(512) void select_block(
    const float* __restrict__ S, int* __restrict__ sel)
{
  const int b = blockIdx.x;
  const int tid = threadIdx.x;
  const int w = tid >> 6;          // 0..7
  const int lane = tid & 63;
  const float* Sb = S + (size_t)b * NN * NN + 4 * tid;
  int* selb = sel + b * NN;

  __shared__ u64 partial[2][8];

  for (int i = tid; i < NN; i += 512) selb[i] = 0x7fffffff;
  __syncthreads();

  unsigned mybits = 0;                 // used flags for my 4 columns
  const unsigned base = 2047u - 4u * (unsigned)tid;

  auto stepf = [&](float4 v, int t) {
    u64 k0 = (mybits & 1u) ? 0 : (((u64)mapf(v.x) << 32) | (base - 0u));
    u64 k1 = (mybits & 2u) ? 0 : (((u64)mapf(v.y) << 32) | (base - 1u));
    u64 k2 = (mybits & 4u) ? 0 : (((u64)mapf(v.z) << 32) | (base - 2u));
    u64 k3 = (mybits & 8u) ? 0 : (((u64)mapf(v.w) << 32) | (base - 3u));
    u64 k = k0 > k1 ? k0 : k1;
    if (k2 > k) k = k2;
    if (k3 > k) k = k3;
    #pragma unroll
    for (int off = 1; off < 64; off <<= 1) {
      u64 o = shflx_u64(k, off);
      if (o > k) k = o;
    }
    if (lane == 0) partial[t & 1][w] = k;
    __syncthreads();
    u64 pk = partial[t & 1][lane & 7];
    #pragma unroll
    for (int off = 1; off < 8; off <<= 1) {
      u64 o = shflx_u64(pk, off);
      if (o > pk) pk = o;
    }
    const int idx = 2047 - (int)(pk & 0x7ff);
    if ((idx >> 2) == tid) mybits |= 1u << (idx & 3);
    if (tid == 0) selb[idx] = t;
  };

  float4 r0 = *(const float4*)(Sb + (size_t)0 * NN);
  float4 r1 = *(const float4*)(Sb + (size_t)1 * NN);
  float4 r2 = *(const float4*)(Sb + (size_t)2 * NN);
  float4 r3 = *(const float4*)(Sb + (size_t)3 * NN);
  for (int t = 0; t < NN; t += 4) {
    const size_t p4 = (size_t)((t + 4 < NN) ? t + 4 : NN - 1) * NN;
    const size_t p5 = (size_t)((t + 5 < NN) ? t + 5 : NN - 1) * NN;
    const size_t p6 = (size_t)((t + 6 < NN) ? t + 6 : NN - 1) * NN;
    const size_t p7 = (size_t)((t + 7 < NN) ? t + 7 : NN - 1) * NN;
    stepf(r0, t);     r0 = *(const float4*)(Sb + p4);
    stepf(r1, t + 1); r1 = *(const float4*)(Sb + p5);
    stepf(r2, t + 2); r2 = *(const float4*)(Sb + p6);
    stepf(r3, t + 3); r3 = *(const float4*)(Sb + p7);
  }
}

// ---------------------------------------------------------------------------
// Phase E: in-place masked softmax per row. Row t masks n iff sel[n] < t.
// ---------------------------------------------------------------------------
__global__ __launch_bounds__(256) void softmax_kernel(
    float* __restrict__ out, const int* __restrict__ sel)
{
  const int t = blockIdx.x;
  const int b = blockIdx.y;
  const int tid = threadIdx.x;
  float* row = out + ((size_t)b * NN + t) * NN;
  const int* selb = sel + b * NN;
  __shared__ float red[8];

  float v[8];
  int sl[8];
  #pragma unroll
  for (int u = 0; u < 2; ++u) {
    float4 f = *(const float4*)(row + u * 1024 + tid * 4);
    int4 s4 = *(const int4*)(selb + u * 1024 + tid * 4);
    v[u * 4 + 0] = f.x; v[u * 4 + 1] = f.y; v[u * 4 + 2] = f.z; v[u * 4 + 3] = f.w;
    sl[u * 4 + 0] = s4.x; sl[u * 4 + 1] = s4.y; sl[u * 4 + 2] = s4.z; sl[u * 4 + 3] = s4.w;
  }

  float mx = -3.0e38f;
  #pragma unroll
  for (int e = 0; e < 8; ++e)
    if (sl[e] >= t) mx = fmaxf(mx, v[e]);
  #pragma unroll
  for (int off = 1; off < 64; off <<= 1) mx = fmaxf(mx, __shfl_xor(mx, off));
  if ((tid & 63) == 0) red[tid >> 6] = mx;
  __syncthreads();
  mx = fmaxf(fmaxf(red[0], red[1]), fmaxf(red[2], red[3]));

  float e8[8];
  float sum = 0.f;
  #pragma unroll
  for (int e = 0; e < 8; ++e) {
    float ex = (sl[e] >= t) ? __expf(v[e] - mx) : 0.f;
    e8[e] = ex;
    sum += ex;
  }
  #pragma unroll
  for (int off = 1; off < 64; off <<= 1) sum += __shfl_xor(sum, off);
  if ((tid & 63) == 0) red[4 + (tid >> 6)] = sum;
  __syncthreads();
  sum = red[4] + red[5] + red[6] + red[7];
  const float inv = 1.f / sum;

  #pragma unroll
  for (int u = 0; u < 2; ++u) {
    float4 o;
    o.x = e8[u * 4 + 0] * inv; o.y = e8[u * 4 + 1] * inv;
    o.z = e8[u * 4 + 2] * inv; o.w = e8[u * 4 + 3] * inv;
    *(float4*)(row + u * 1024 + tid * 4) = o;
  }
}

// ---------------------------------------------------------------------------
// ws layout (floats): keys[4194304] | Q[4194304] | (unused 8192) |
//                     Hslow(u64 4096) | sel[16384]   ~ 33.7 MB
// ---------------------------------------------------------------------------
extern "C" void kernel_launch(void* const* d_in, const int* in_sizes, int n_in,
                              void* d_out, int out_size, void* d_ws, size_t ws_size,
                              hipStream_t stream)
{
  (void)in_sizes; (void)n_in; (void)out_size; (void)ws_size;
  const float* emb  = (const float*)d_in[0];
  const float* z_g  = (const float*)d_in[1];
  const float* dec  = (const float*)d_in[2];
  const float* h0   = (const float*)d_in[3];
  const float* w_ih = (const float*)d_in[4];
  const float* w_hh = (const float*)d_in[5];
  const float* b_ih = (const float*)d_in[6];
  const float* b_hh = (const float*)d_in[7];
  const float* Wq   = (const float*)d_in[8];
  const float* bq   = (const float*)d_in[9];
  const float* Wk   = (const float*)d_in[10];
  const float* bk   = (const float*)d_in[11];
  float* out = (float*)d_out;
  float* ws  = (float*)d_ws;

  float* keys  = ws;
  float* Q     = ws + 4194304;
  u64*   Hslow = (u64*)(ws + 8396800);
  int*   sel   = (int*)(ws + 8404992);

  lstm_kernel<<<dim3(NB, 8), 1024, 0, stream>>>(
      z_g, dec, h0, w_ih, w_hh, b_ih, b_hh, Wq, bq, Q, Hslow);

  // keys = emb @ Wk.T + bk  ([16384,256] x [256,256]^T)
  gemm128<<<dim3(MM / 128, (NB * NN) / 128, 1), 256, 0, stream>>>(
      emb, Wk, keys, bk, MM, MM, 0, 0, 0);

  // S[b] = Q[b] @ keys[b].T -> straight into d_out
  gemm128<<<dim3(NN / 128, NN / 128, NB), 256, 0, stream>>>(
      Q, keys, out, nullptr, MM, NN,
      (long)NN * MM, (long)NN * MM, (long)NN * NN);

  select_block<<<NB, 512, 0, stream>>>(out, sel);

  softmax_kernel<<<dim3(NN, NB), 256, 0, stream>>>(out, sel);
}